// Round 1
// 1369.700 us; speedup vs baseline: 1.3508x; 1.3508x over previous
//
#include <hip/hip_runtime.h>
#include <hip/hip_bf16.h>

#define K_DIM 4096
#define N_DIM 11008
#define M_DIM 8192

typedef _Float16 f16;
typedef f16 f16x4 __attribute__((ext_vector_type(4)));
typedef f16 f16x8 __attribute__((ext_vector_type(8)));
typedef float f32x4 __attribute__((ext_vector_type(4)));

typedef __attribute__((address_space(1))) unsigned int gu32;
typedef __attribute__((address_space(3))) unsigned int lu32;

__device__ __forceinline__ void g2l16(const void* gp, void* lp) {
    __builtin_amdgcn_global_load_lds((gu32*)gp, (lu32*)lp, 16, 0, 0);
}

// ---------------------------------------------------------------------------
// Prepass 1: W int32 -> f16 (int8 values are exact in f16)
// ---------------------------------------------------------------------------
__global__ __launch_bounds__(256) void convw_kernel(const int* __restrict__ Wq,
                                                    f16* __restrict__ Wh) {
    const size_t n4 = (size_t)N_DIM * K_DIM / 4;  // 11,272,192 int4 groups
    const size_t stride = (size_t)gridDim.x * 256;
    const int4* src = (const int4*)Wq;
    f16x4* dst = (f16x4*)Wh;
    for (size_t i = (size_t)blockIdx.x * 256 + threadIdx.x; i < n4; i += stride) {
        int4 a = src[i];
        f16x4 o = {(f16)a.x, (f16)a.y, (f16)a.z, (f16)a.w};
        dst[i] = o;
    }
}

// ---------------------------------------------------------------------------
// Prepass 2: X f32 -> f16, plus rowsum of the CONVERTED values (consistency
// with the zp correction term). One 256-thread block per row.
// ---------------------------------------------------------------------------
__global__ __launch_bounds__(256) void convx_kernel(const float* __restrict__ X,
                                                    f16* __restrict__ Xh,
                                                    float* __restrict__ rs) {
    const int row = blockIdx.x;
    const int t = threadIdx.x;
    const float4* xr = (const float4*)(X + (size_t)row * K_DIM);
    f16x4* xo = (f16x4*)(Xh + (size_t)row * K_DIM);
    float s = 0.f;
#pragma unroll
    for (int j = 0; j < 4; ++j) {
        float4 v = xr[t + 256 * j];
        f16x4 h = {(f16)v.x, (f16)v.y, (f16)v.z, (f16)v.w};
        xo[t + 256 * j] = h;
        s += (float)h[0] + (float)h[1] + (float)h[2] + (float)h[3];
    }
#pragma unroll
    for (int off = 32; off > 0; off >>= 1) s += __shfl_down(s, off);
    __shared__ float part[4];
    if ((t & 63) == 0) part[t >> 6] = s;
    __syncthreads();
    if (t == 0) rs[row] = part[0] + part[1] + part[2] + part[3];
}

// ---------------------------------------------------------------------------
// GEMM: 128x128 tile, BK=32, f16 MFMA 16x16x32, m97 structure.
// LDS rows are 64 B = 4 groups of 16 B. XOR swizzle: logical group g of row r
// is stored at physical slot g ^ ((r>>1)&3). global_load_lds forces LDS dest
// = base + lane*16, so the swizzle is applied on the GLOBAL address side:
// lane l fetches logical group (l&3) ^ ((l>>3)&3) of its row. Reads of
// logical group q use physical slot q ^ ((ln>>1)&3) -> 2 lanes/bank (free).
//   y[m,n] = scale[n]*(dot[m,n] - zp[n]*rowsum[m]) + bias[n]
//
// Grid order (R1): blockIdx.x = m-tile (fast), blockIdx.y = n-tile (slow).
// HW dispatches x-fastest, so concurrently-resident blocks share a few 1 MB
// W panels and sweep X; concurrent working set = Xh(67 MB) + few W panels
// << 256 MB L3 -> Xh stays L3-resident for the whole kernel and Wh streams
// exactly once. (Previous n-fastest order re-fetched Wh ~52x -> 4.7 GB.)
// ---------------------------------------------------------------------------
__global__ __launch_bounds__(256, 2)
void qlin_gemm(const f16* __restrict__ Xh, const f16* __restrict__ Wh,
               const float* __restrict__ scale, const float* __restrict__ zp,
               const float* __restrict__ bias, const float* __restrict__ rowsum,
               float* __restrict__ out) {
    __shared__ char lx[8192];  // 128 rows x 64 B (32 f16)
    __shared__ char lw[8192];

    const int tid = threadIdx.x;
    const int l = tid & 63;
    const int w = tid >> 6;
    const int wm = w & 1;
    const int wn = w >> 1;
    const int q = l >> 4;
    const int ln = l & 15;

    const int m0 = blockIdx.x * 128;  // m-tile varies fastest across blocks
    const int n0 = blockIdx.y * 128;

    const int sg = (l & 3) ^ ((l >> 3) & 3);  // staging logical group (lane-const)
    const size_t rowbytes = K_DIM * 2;

    // wave w, round c stages rows c*64 + w*16 + (l>>2); c handled by +64-row offset
    const char* xg = (const char*)Xh + (size_t)(m0 + w * 16 + (l >> 2)) * rowbytes + sg * 16;
    const char* wg = (const char*)Wh + (size_t)(n0 + w * 16 + (l >> 2)) * rowbytes + sg * 16;
    char* lxp = lx + w * 1024 + l * 16;
    char* lwp = lw + w * 1024 + l * 16;

    const int rsw = (q ^ ((ln >> 1) & 3)) * 16;  // read slot byte offset (lane-const)
    const char* lxr = lx + (wm * 64 + ln) * 64 + rsw;
    const char* lwr = lw + (wn * 64 + ln) * 64 + rsw;

    f32x4 acc[4][4] = {};

    for (int kt = 0; kt < 128; ++kt) {
        const size_t k0 = (size_t)kt * 64;  // bytes into the row
        g2l16(xg + k0, lxp);
        g2l16(xg + 64 * rowbytes + k0, lxp + 4096);
        g2l16(wg + k0, lwp);
        g2l16(wg + 64 * rowbytes + k0, lwp + 4096);
        __syncthreads();  // vmcnt(0) drain -> tiles ready

        f16x8 af[4], bf[4];
#pragma unroll
        for (int i = 0; i < 4; ++i) af[i] = *(const f16x8*)(lxr + i * 1024);
#pragma unroll
        for (int j = 0; j < 4; ++j) bf[j] = *(const f16x8*)(lwr + j * 1024);
#pragma unroll
        for (int i = 0; i < 4; ++i)
#pragma unroll
            for (int j = 0; j < 4; ++j)
                acc[i][j] = __builtin_amdgcn_mfma_f32_16x16x32_f16(af[i], bf[j], acc[i][j], 0, 0, 0);
        __syncthreads();  // all reads done before next restage
    }

    // epilogue
    float sc[4], zv[4], bv[4];
    int ncol[4];
#pragma unroll
    for (int j = 0; j < 4; ++j) {
        const int n = n0 + wn * 64 + j * 16 + ln;
        ncol[j] = n;
        sc[j] = scale[n];
        zv[j] = zp[n];
        bv[j] = bias[n];
    }
#pragma unroll
    for (int i = 0; i < 4; ++i) {
#pragma unroll
        for (int r = 0; r < 4; ++r) {
            const int m = m0 + wm * 64 + i * 16 + q * 4 + r;
            const float rsm = rowsum[m];
            const size_t rowoff = (size_t)m * N_DIM;
#pragma unroll
            for (int j = 0; j < 4; ++j) {
                out[rowoff + ncol[j]] = sc[j] * (acc[i][j][r] - zv[j] * rsm) + bv[j];
            }
        }
    }
}

extern "C" void kernel_launch(void* const* d_in, const int* in_sizes, int n_in,
                              void* d_out, int out_size, void* d_ws, size_t ws_size,
                              hipStream_t stream) {
    const float* X     = (const float*)d_in[0];
    const int*   Wq    = (const int*)d_in[1];
    const float* scale = (const float*)d_in[2];
    const float* zp    = (const float*)d_in[3];
    const float* bias  = (const float*)d_in[4];
    float* out = (float*)d_out;

    // ws layout: Wh (90,177,536 B) | Xh (67,108,864 B) | rowsum (32 KB)
    f16* Wh = (f16*)d_ws;
    f16* Xh = (f16*)((char*)d_ws + (size_t)N_DIM * K_DIM * 2);
    float* rowsum = (float*)((char*)d_ws + (size_t)N_DIM * K_DIM * 2 + (size_t)M_DIM * K_DIM * 2);

    convw_kernel<<<4096, 256, 0, stream>>>(Wq, Wh);
    convx_kernel<<<M_DIM, 256, 0, stream>>>(X, Xh, rowsum);

    dim3 grid(M_DIM / 128, N_DIM / 128);  // (64, 86): m-fastest for W stream-once
    qlin_gemm<<<grid, 256, 0, stream>>>(Xh, Wh, scale, zp, bias, rowsum, out);
}

// Round 2
// 1159.865 us; speedup vs baseline: 1.5952x; 1.1809x over previous
//
#include <hip/hip_runtime.h>

#define K_DIM 4096
#define N_DIM 11008
#define M_DIM 8192
#define NT 64  // K / 64

typedef _Float16 f16;
typedef f16 f16x4 __attribute__((ext_vector_type(4)));
typedef f16 f16x8 __attribute__((ext_vector_type(8)));
typedef float f32x4 __attribute__((ext_vector_type(4)));

typedef __attribute__((address_space(1))) unsigned int gu32;
typedef __attribute__((address_space(3))) unsigned int lu32;

__device__ __forceinline__ void g2l16(const void* gp, void* lp) {
    __builtin_amdgcn_global_load_lds((gu32*)gp, (lu32*)lp, 16, 0, 0);
}

// ---------------------------------------------------------------------------
// Prepass 1: W int32 -> f16 (int8 values are exact in f16)
// ---------------------------------------------------------------------------
__global__ __launch_bounds__(256) void convw_kernel(const int* __restrict__ Wq,
                                                    f16* __restrict__ Wh) {
    const size_t n4 = (size_t)N_DIM * K_DIM / 4;
    const size_t stride = (size_t)gridDim.x * 256;
    const int4* src = (const int4*)Wq;
    f16x4* dst = (f16x4*)Wh;
    for (size_t i = (size_t)blockIdx.x * 256 + threadIdx.x; i < n4; i += stride) {
        int4 a = src[i];
        f16x4 o = {(f16)a.x, (f16)a.y, (f16)a.z, (f16)a.w};
        dst[i] = o;
    }
}

// ---------------------------------------------------------------------------
// Prepass 2: X f32 -> f16 + rowsum of converted values
// ---------------------------------------------------------------------------
__global__ __launch_bounds__(256) void convx_kernel(const float* __restrict__ X,
                                                    f16* __restrict__ Xh,
                                                    float* __restrict__ rs) {
    const int row = blockIdx.x;
    const int t = threadIdx.x;
    const float4* xr = (const float4*)(X + (size_t)row * K_DIM);
    f16x4* xo = (f16x4*)(Xh + (size_t)row * K_DIM);
    float s = 0.f;
#pragma unroll
    for (int j = 0; j < 4; ++j) {
        float4 v = xr[t + 256 * j];
        f16x4 h = {(f16)v.x, (f16)v.y, (f16)v.z, (f16)v.w};
        xo[t + 256 * j] = h;
        s += (float)h[0] + (float)h[1] + (float)h[2] + (float)h[3];
    }
#pragma unroll
    for (int off = 32; off > 0; off >>= 1) s += __shfl_down(s, off);
    __shared__ float part[4];
    if ((t & 63) == 0) part[t >> 6] = s;
    __syncthreads();
    if (t == 0) rs[row] = part[0] + part[1] + part[2] + part[3];
}

// ---------------------------------------------------------------------------
// GEMM: 256x256 tile, BK=64, 8 waves (2Mx4N), 4 phases/K-tile, counted vmcnt.
// LDS 128 KB: buf p at p*65536 (A 32K | B 32K). Rows are 128 B = 8 slots of
// 16 B; phys slot = logical ^ (row&7) (XOR swizzle applied on the GLOBAL
// source side since global_load_lds writes linearly).
//
// Phase schedule per tile T (cur = T&1), MFMA quadrant order
// (m0-3,n0-1)->(m0-3,n2-3)->(m4-7,n2-3)->(m4-7,n0-1); staging of tile T+2
// goes into buf cur's regions that died in the PREVIOUS phase:
//   P0: stage tile T+1 B-chunks 2,3 -> buf cur^1   (that buf fully dead)
//   P1: stage A-chunks 0,2 (rows 0-63,128-191; dead after P0)
//   P2: stage B-chunks 0,1 (all B dead after P1)
//   P3: stage A-chunks 1,3 (rows 64-127,192-255; dead after P2), vmcnt(6)
// vmcnt(6) leaves exactly the 6 loads issued at P1-P3 (tile T+2) in flight
// and forces tile T+1's 8 loads complete before its publish barrier.
// ---------------------------------------------------------------------------
__global__ __launch_bounds__(512, 2)
void qlin_gemm(const f16* __restrict__ Xh, const f16* __restrict__ Wh,
               const float* __restrict__ scale, const float* __restrict__ zp,
               const float* __restrict__ bias, const float* __restrict__ rowsum,
               float* __restrict__ out) {
    extern __shared__ __align__(16) char smem[];

    const int t = threadIdx.x;
    const int l = t & 63;
    const int w = t >> 6;
    const int wm = w >> 2;  // 0..1 -> rows wm*128
    const int wn = w & 3;   // 0..3 -> cols wn*64
    const int q = l >> 4;
    const int ln = l & 15;

    const int m0 = blockIdx.x * 256;  // m-fastest dispatch (R1 win)
    const int n0 = blockIdx.y * 256;

    // staging: thread t handles local row t>>3 of a 64-row chunk, phys slot t&7
    const int srow = t >> 3;
    const int sslot = (t & 7) ^ (srow & 7);
    const char* xbase = (const char*)Xh + ((size_t)(m0 + srow) << 13) + (sslot << 4);
    const char* wbase = (const char*)Wh + ((size_t)(n0 + srow) << 13) + (sslot << 4);
    char* ldst = smem + t * 16;

#define STG_A(p, c, T) g2l16(xbase + ((size_t)(c) << 19) + ((size_t)(T) << 7), ldst + (p)*65536 + (c)*8192)
#define STG_B(p, c, T) g2l16(wbase + ((size_t)(c) << 19) + ((size_t)(T) << 7), ldst + (p)*65536 + 32768 + (c)*8192)
#define SB __builtin_amdgcn_sched_barrier(0)
#define BAR __builtin_amdgcn_s_barrier()
#define LGKM0 asm volatile("s_waitcnt lgkmcnt(0)" ::: "memory")

    // ds_read lane offsets: row = base + frag*16 + ln, slot = (q + kk*4) ^ (ln&7)
    const int xs = ln & 7;
    int offA[2], offB[2];
    offA[0] = (wm * 128 + ln) * 128 + ((q ^ xs) << 4);
    offA[1] = (wm * 128 + ln) * 128 + (((q + 4) ^ xs) << 4);
    offB[0] = 32768 + (wn * 64 + ln) * 128 + ((q ^ xs) << 4);
    offB[1] = 32768 + (wn * 64 + ln) * 128 + (((q + 4) ^ xs) << 4);

    f32x4 acc[8][4] = {};
    f16x8 aR[4][2], bR[4][2];

    // prologue: tile 0 (8 chunks) + tile 1 first 6 chunks; vmcnt(6) -> tile 0 ready
    STG_A(0, 0, 0); STG_A(0, 2, 0); STG_B(0, 0, 0); STG_B(0, 1, 0);
    STG_A(0, 1, 0); STG_A(0, 3, 0); STG_B(0, 2, 0); STG_B(0, 3, 0);
    STG_A(1, 0, 1); STG_A(1, 2, 1); STG_B(1, 0, 1); STG_B(1, 1, 1);
    STG_A(1, 1, 1); STG_A(1, 3, 1);
    asm volatile("s_waitcnt vmcnt(6)" ::: "memory");
    BAR;

#define TILE(T, CUR)                                                                               \
    do {                                                                                           \
        /* ---- P0: read a[0..3], b[0..1]; stage tile T+1 B2,B3 -> other buf ---- */               \
        _Pragma("unroll") for (int kk = 0; kk < 2; ++kk) {                                         \
            _Pragma("unroll") for (int i = 0; i < 4; ++i)                                          \
                aR[i][kk] = *(const f16x8*)(smem + (CUR)*65536 + offA[kk] + i * 2048);             \
            _Pragma("unroll") for (int j = 0; j < 2; ++j)                                          \
                bR[j][kk] = *(const f16x8*)(smem + (CUR)*65536 + offB[kk] + j * 2048);             \
        }                                                                                          \
        if ((T) + 1 < NT) { STG_B(((CUR) ^ 1), 2, (T) + 1); STG_B(((CUR) ^ 1), 3, (T) + 1); }      \
        SB; BAR; LGKM0; SB;                                                                        \
        __builtin_amdgcn_s_setprio(1);                                                             \
        _Pragma("unroll") for (int kk = 0; kk < 2; ++kk)                                           \
            _Pragma("unroll") for (int i = 0; i < 4; ++i)                                          \
                _Pragma("unroll") for (int j = 0; j < 2; ++j)                                      \
                    acc[i][j] = __builtin_amdgcn_mfma_f32_16x16x32_f16(aR[i][kk], bR[j][kk],       \
                                                                       acc[i][j], 0, 0, 0);        \
        __builtin_amdgcn_s_setprio(0);                                                             \
        SB; BAR; SB;                                                                               \
        /* ---- P1: read b[2..3]; stage tile T+2 A0,A2 -> cur buf ---- */                          \
        _Pragma("unroll") for (int kk = 0; kk < 2; ++kk) {                                         \
            _Pragma("unroll") for (int j = 0; j < 2; ++j)                                          \
                bR[2 + j][kk] = *(const f16x8*)(smem + (CUR)*65536 + offB[kk] + (2 + j) * 2048);   \
        }                                                                                          \
        if ((T) + 2 < NT) { STG_A((CUR), 0, (T) + 2); STG_A((CUR), 2, (T) + 2); }                  \
        SB; BAR; LGKM0; SB;                                                                        \
        __builtin_amdgcn_s_setprio(1);                                                             \
        _Pragma("unroll") for (int kk = 0; kk < 2; ++kk)                                           \
            _Pragma("unroll") for (int i = 0; i < 4; ++i)                                          \
                _Pragma("unroll") for (int j = 0; j < 2; ++j)                                      \
                    acc[i][2 + j] = __builtin_amdgcn_mfma_f32_16x16x32_f16(aR[i][kk],              \
                                        bR[2 + j][kk], acc[i][2 + j], 0, 0, 0);                    \
        __builtin_amdgcn_s_setprio(0);                                                             \
        SB; BAR; SB;                                                                               \
        /* ---- P2: read a[4..7]; stage tile T+2 B0,B1 -> cur buf ---- */                          \
        _Pragma("unroll") for (int kk = 0; kk < 2; ++kk) {                                         \
            _Pragma("unroll") for (int i = 0; i < 4; ++i)                                          \
                aR[i][kk] = *(const f16x8*)(smem + (CUR)*65536 + offA[kk] + (4 + i) * 2048);       \
        }                                                                                          \
        if ((T) + 2 < NT) { STG_B((CUR), 0, (T) + 2); STG_B((CUR), 1, (T) + 2); }                  \
        SB; BAR; LGKM0; SB;                                                                        \
        __builtin_amdgcn_s_setprio(1);                                                             \
        _Pragma("unroll") for (int kk = 0; kk < 2; ++kk)                                           \
            _Pragma("unroll") for (int i = 0; i < 4; ++i)                                          \
                _Pragma("unroll") for (int j = 0; j < 2; ++j)                                      \
                    acc[4 + i][2 + j] = __builtin_amdgcn_mfma_f32_16x16x32_f16(aR[i][kk],          \
                                            bR[2 + j][kk], acc[4 + i][2 + j], 0, 0, 0);            \
        __builtin_amdgcn_s_setprio(0);                                                             \
        SB; BAR; SB;                                                                               \
        /* ---- P3: stage tile T+2 A1,A3; vmcnt(6) publishes tile T+1 ---- */                      \
        if ((T) + 2 < NT) {                                                                        \
            STG_A((CUR), 1, (T) + 2); STG_A((CUR), 3, (T) + 2);                                    \
            asm volatile("s_waitcnt vmcnt(6)" ::: "memory");                                       \
        } else {                                                                                   \
            asm volatile("s_waitcnt vmcnt(0)" ::: "memory");                                       \
        }                                                                                          \
        SB; BAR; SB;                                                                               \
        __builtin_amdgcn_s_setprio(1);                                                             \
        _Pragma("unroll") for (int kk = 0; kk < 2; ++kk)                                           \
            _Pragma("unroll") for (int i = 0; i < 4; ++i)                                          \
                _Pragma("unroll") for (int j = 0; j < 2; ++j)                                      \
                    acc[4 + i][j] = __builtin_amdgcn_mfma_f32_16x16x32_f16(aR[i][kk], bR[j][kk],   \
                                        acc[4 + i][j], 0, 0, 0);                                   \
        __builtin_amdgcn_s_setprio(0);                                                             \
        SB; BAR; SB;                                                                               \
    } while (0)

#pragma unroll 1
    for (int Tp = 0; Tp < NT / 2; ++Tp) {
        TILE(2 * Tp, 0);
        TILE(2 * Tp + 1, 1);
    }
#undef TILE
#undef STG_A
#undef STG_B

    // epilogue: y[m,n] = scale[n]*(dot - zp[n]*rowsum[m]) + bias[n]
    float sc[4], zv[4], bv[4];
    int ncol[4];
#pragma unroll
    for (int j = 0; j < 4; ++j) {
        const int n = n0 + wn * 64 + j * 16 + ln;
        ncol[j] = n;
        sc[j] = scale[n];
        zv[j] = zp[n];
        bv[j] = bias[n];
    }
#pragma unroll
    for (int i = 0; i < 8; ++i) {
#pragma unroll
        for (int r = 0; r < 4; ++r) {
            const int m = m0 + wm * 128 + i * 16 + q * 4 + r;
            const float rsm = rowsum[m];
            const size_t rowoff = (size_t)m * N_DIM;
#pragma unroll
            for (int j = 0; j < 4; ++j) {
                out[rowoff + ncol[j]] = sc[j] * (acc[i][j][r] - zv[j] * rsm) + bv[j];
            }
        }
    }
}

extern "C" void kernel_launch(void* const* d_in, const int* in_sizes, int n_in,
                              void* d_out, int out_size, void* d_ws, size_t ws_size,
                              hipStream_t stream) {
    const float* X     = (const float*)d_in[0];
    const int*   Wq    = (const int*)d_in[1];
    const float* scale = (const float*)d_in[2];
    const float* zp    = (const float*)d_in[3];
    const float* bias  = (const float*)d_in[4];
    float* out = (float*)d_out;

    // ws layout: Wh (90,177,536 B) | Xh (67,108,864 B) | rowsum (32 KB)
    f16* Wh = (f16*)d_ws;
    f16* Xh = (f16*)((char*)d_ws + (size_t)N_DIM * K_DIM * 2);
    float* rowsum = (float*)((char*)d_ws + (size_t)N_DIM * K_DIM * 2 + (size_t)M_DIM * K_DIM * 2);

    static bool attr_done = false;
    if (!attr_done) {
        (void)hipFuncSetAttribute((const void*)qlin_gemm,
                                  hipFuncAttributeMaxDynamicSharedMemorySize, 131072);
        attr_done = true;
    }

    convw_kernel<<<4096, 256, 0, stream>>>(Wq, Wh);
    convx_kernel<<<M_DIM, 256, 0, stream>>>(X, Xh, rowsum);

    dim3 grid(M_DIM / 256, N_DIM / 256);  // (32, 43): m-fastest for W stream-once
    qlin_gemm<<<grid, 512, 131072, stream>>>(Xh, Wh, scale, zp, bias, rowsum, out);
}

// Round 3
// 1102.662 us; speedup vs baseline: 1.6779x; 1.0519x over previous
//
#include <hip/hip_runtime.h>

#define K_DIM 4096
#define N_DIM 11008
#define M_DIM 8192
#define NT 64  // K / 64

typedef _Float16 f16;
typedef f16 f16x4 __attribute__((ext_vector_type(4)));
typedef f16 f16x8 __attribute__((ext_vector_type(8)));
typedef float f32x4 __attribute__((ext_vector_type(4)));

typedef __attribute__((address_space(1))) unsigned int gu32;
typedef __attribute__((address_space(3))) unsigned int lu32;

__device__ __forceinline__ void g2l16(const void* gp, void* lp) {
    __builtin_amdgcn_global_load_lds((gu32*)gp, (lu32*)lp, 16, 0, 0);
}

// ---------------------------------------------------------------------------
// Prepass 1: W int32 -> f16 (int8 values are exact in f16)
// ---------------------------------------------------------------------------
__global__ __launch_bounds__(256) void convw_kernel(const int* __restrict__ Wq,
                                                    f16* __restrict__ Wh) {
    const size_t n4 = (size_t)N_DIM * K_DIM / 4;
    const size_t stride = (size_t)gridDim.x * 256;
    const int4* src = (const int4*)Wq;
    f16x4* dst = (f16x4*)Wh;
    for (size_t i = (size_t)blockIdx.x * 256 + threadIdx.x; i < n4; i += stride) {
        int4 a = src[i];
        f16x4 o = {(f16)a.x, (f16)a.y, (f16)a.z, (f16)a.w};
        dst[i] = o;
    }
}

// ---------------------------------------------------------------------------
// Prepass 2: X f32 -> f16 + rowsum of converted values
// ---------------------------------------------------------------------------
__global__ __launch_bounds__(256) void convx_kernel(const float* __restrict__ X,
                                                    f16* __restrict__ Xh,
                                                    float* __restrict__ rs) {
    const int row = blockIdx.x;
    const int t = threadIdx.x;
    const float4* xr = (const float4*)(X + (size_t)row * K_DIM);
    f16x4* xo = (f16x4*)(Xh + (size_t)row * K_DIM);
    float s = 0.f;
#pragma unroll
    for (int j = 0; j < 4; ++j) {
        float4 v = xr[t + 256 * j];
        f16x4 h = {(f16)v.x, (f16)v.y, (f16)v.z, (f16)v.w};
        xo[t + 256 * j] = h;
        s += (float)h[0] + (float)h[1] + (float)h[2] + (float)h[3];
    }
#pragma unroll
    for (int off = 32; off > 0; off >>= 1) s += __shfl_down(s, off);
    __shared__ float part[4];
    if ((t & 63) == 0) part[t >> 6] = s;
    __syncthreads();
    if (t == 0) rs[row] = part[0] + part[1] + part[2] + part[3];
}

// ---------------------------------------------------------------------------
// GEMM: 256x256 tile, BK=64, 8 waves (2Mx4N). Shifted pipeline (R3): every
// compartment's MFMA consumes fragments ds_read in the PREVIOUS compartment;
// this compartment's ds_reads (next quadrant / next tile) interleave with the
// MFMAs (separate pipes). One lgkmcnt(0)+s_barrier per compartment, at the
// END, so all waves' reads are drained before any barrier that precedes a
// re-stage of that region (cross-wave WAR safety for global_load_lds).
//
// Quadrants: Q0(aLo,b01)->acc[0-3][0-1], Q1(aLo,b23)->acc[0-3][2-3],
//            Q2(aHi,b23)->acc[4-7][2-3], Q3(aHi,b01)->acc[4-7][0-1].
// Region deaths (tile T, buf cur): aLo read @CQ3(T-1); b23 @CQ0(T);
// aHi @CQ1(T); B chunks fully dead after CQ0(T).
// Stages (2 chunks/compartment, tile T+2 -> cur): CQ0:A0,A2  CQ1:B0,B1
// CQ2:A1,A3 + vmcnt(6)  CQ3:B2,B3; next-tile reads (buf cur^1) in CQ3.
// vmcnt(6) at CQ2-end leaves exactly the 6 newest chunks (T+2's A0A2,B0B1,
// A1A3) in flight => everything older (all 8 of T+1) landed before CQ3.
// ---------------------------------------------------------------------------
__global__ __launch_bounds__(512, 2)
void qlin_gemm(const f16* __restrict__ Xh, const f16* __restrict__ Wh,
               const float* __restrict__ scale, const float* __restrict__ zp,
               const float* __restrict__ bias, const float* __restrict__ rowsum,
               float* __restrict__ out) {
    extern __shared__ __align__(16) char smem[];

    const int t = threadIdx.x;
    const int l = t & 63;
    const int w = t >> 6;
    const int wm = w >> 2;  // 0..1 -> rows wm*128
    const int wn = w & 3;   // 0..3 -> cols wn*64
    const int q = l >> 4;
    const int ln = l & 15;

    const int m0 = blockIdx.x * 256;  // m-fastest dispatch (R1 win)
    const int n0 = blockIdx.y * 256;

    // staging: thread t handles local row t>>3 of a 64-row chunk, phys slot t&7
    const int srow = t >> 3;
    const int sslot = (t & 7) ^ (srow & 7);
    const char* xbase = (const char*)Xh + ((size_t)(m0 + srow) << 13) + (sslot << 4);
    const char* wbase = (const char*)Wh + ((size_t)(n0 + srow) << 13) + (sslot << 4);
    char* ldst = smem + t * 16;

#define STG_A(p, c, T) g2l16(xbase + ((size_t)(c) << 19) + ((size_t)(T) << 7), ldst + (p)*65536 + (c)*8192)
#define STG_B(p, c, T) g2l16(wbase + ((size_t)(c) << 19) + ((size_t)(T) << 7), ldst + (p)*65536 + 32768 + (c)*8192)
#define SB __builtin_amdgcn_sched_barrier(0)
#define BAR __builtin_amdgcn_s_barrier()
#define LGKM0 asm volatile("s_waitcnt lgkmcnt(0)" ::: "memory")
#define VMC6 asm volatile("s_waitcnt vmcnt(6)" ::: "memory")

    // ds_read lane offsets: row = base + frag*16 + ln, phys slot = (q+kk*4) ^ (ln&7)
    const int xs = ln & 7;
    int offA[2], offB[2];
    offA[0] = (wm * 128 + ln) * 128 + ((q ^ xs) << 4);
    offA[1] = (wm * 128 + ln) * 128 + (((q + 4) ^ xs) << 4);
    offB[0] = 32768 + (wn * 64 + ln) * 128 + ((q ^ xs) << 4);
    offB[1] = 32768 + (wn * 64 + ln) * 128 + (((q + 4) ^ xs) << 4);

    f32x4 acc[8][4] = {};
    f16x8 aR[4][2], b01[2][2], b23[2][2];

#define RD_ALO(P)                                                              \
    _Pragma("unroll") for (int kk = 0; kk < 2; ++kk)                           \
    _Pragma("unroll") for (int i = 0; i < 4; ++i)                              \
        aR[i][kk] = *(const f16x8*)(smem + (P)*65536 + offA[kk] + i * 2048)
#define RD_AHI(P)                                                              \
    _Pragma("unroll") for (int kk = 0; kk < 2; ++kk)                           \
    _Pragma("unroll") for (int i = 0; i < 4; ++i)                              \
        aR[i][kk] = *(const f16x8*)(smem + (P)*65536 + offA[kk] + (4 + i) * 2048)
#define RD_B01(P)                                                              \
    _Pragma("unroll") for (int kk = 0; kk < 2; ++kk)                           \
    _Pragma("unroll") for (int j = 0; j < 2; ++j)                              \
        b01[j][kk] = *(const f16x8*)(smem + (P)*65536 + offB[kk] + j * 2048)
#define RD_B23(P)                                                              \
    _Pragma("unroll") for (int kk = 0; kk < 2; ++kk)                           \
    _Pragma("unroll") for (int j = 0; j < 2; ++j)                              \
        b23[j][kk] = *(const f16x8*)(smem + (P)*65536 + offB[kk] + (2 + j) * 2048)
#define MFMA_BLK(I0, J0, BSET)                                                 \
    _Pragma("unroll") for (int kk = 0; kk < 2; ++kk)                           \
    _Pragma("unroll") for (int i = 0; i < 4; ++i)                              \
    _Pragma("unroll") for (int j = 0; j < 2; ++j)                              \
        acc[(I0) + i][(J0) + j] = __builtin_amdgcn_mfma_f32_16x16x32_f16(      \
            aR[i][kk], BSET[j][kk], acc[(I0) + i][(J0) + j], 0, 0, 0)

    // ---- prologue: stage T0 (8) + T1's first 6; vmcnt(6) -> T0 landed ----
    STG_A(0, 0, 0); STG_A(0, 2, 0); STG_B(0, 0, 0); STG_B(0, 1, 0);
    STG_A(0, 1, 0); STG_A(0, 3, 0); STG_B(0, 2, 0); STG_B(0, 3, 0);
    STG_A(1, 0, 1); STG_A(1, 2, 1); STG_B(1, 0, 1); STG_B(1, 1, 1);
    STG_A(1, 1, 1); STG_A(1, 3, 1);
    VMC6; SB; BAR; SB;
    // pre-compartment (== CQ3 of virtual tile -1): load aLo(0), b01(0)
    RD_ALO(0); RD_B01(0);
    STG_B(1, 2, 1); STG_B(1, 3, 1);
    LGKM0; SB; BAR; SB;

#define BODY(T, CUR)                                                           \
    /* CQ0: MFMA Q0 || read b23(T) || stage A0,A2(T+2) */                      \
    RD_B23(CUR);                                                               \
    MFMA_BLK(0, 0, b01);                                                       \
    STG_A(CUR, 0, (T) + 2); STG_A(CUR, 2, (T) + 2);                            \
    LGKM0; SB; BAR; SB;                                                        \
    /* CQ1: MFMA Q1 || read aHi(T) (WAR on aR) || stage B0,B1(T+2) */          \
    MFMA_BLK(0, 2, b23);                                                       \
    RD_AHI(CUR);                                                               \
    STG_B(CUR, 0, (T) + 2); STG_B(CUR, 1, (T) + 2);                            \
    LGKM0; SB; BAR; SB;                                                        \
    /* CQ2: MFMA Q2 || stage A1,A3(T+2); vmcnt(6) publishes T+1 */             \
    MFMA_BLK(4, 2, b23);                                                       \
    STG_A(CUR, 1, (T) + 2); STG_A(CUR, 3, (T) + 2);                            \
    VMC6; SB; BAR; SB;                                                         \
    /* CQ3: MFMA Q3 || read aLo,b01(T+1) from buf^1 || stage B2,B3(T+2) */     \
    MFMA_BLK(4, 0, b01);                                                       \
    RD_ALO((CUR) ^ 1); RD_B01((CUR) ^ 1);                                      \
    STG_B(CUR, 2, (T) + 2); STG_B(CUR, 3, (T) + 2);                            \
    LGKM0; SB; BAR; SB;

    // main loop: tiles 0..61, all guards statically true (T+2 <= 63)
#pragma unroll 1
    for (int Tp = 0; Tp < 31; ++Tp) {
        const int Tb = 2 * Tp;
        BODY(Tb, 0);
        BODY(Tb + 1, 1);
    }
#undef BODY

    // ---- tail: tile 62 (buf0, no stages) ----
    RD_B23(0);
    MFMA_BLK(0, 0, b01);
    MFMA_BLK(0, 2, b23);
    RD_AHI(0);
    MFMA_BLK(4, 2, b23);
    // T63's chunks were staged by all waves through CQ3(61); publish them
    asm volatile("s_waitcnt vmcnt(0)" ::: "memory");
    SB; BAR; SB;
    MFMA_BLK(4, 0, b01);
    RD_ALO(1); RD_B01(1); RD_B23(1);
    // ---- tail: tile 63 (buf1, registers only after reads; no barriers) ----
    MFMA_BLK(0, 0, b01);
    MFMA_BLK(0, 2, b23);
    RD_AHI(1);
    MFMA_BLK(4, 2, b23);
    MFMA_BLK(4, 0, b01);

    // epilogue: y[m,n] = scale[n]*(dot - zp[n]*rowsum[m]) + bias[n]
    float sc[4], zv[4], bv[4];
    int ncol[4];
#pragma unroll
    for (int j = 0; j < 4; ++j) {
        const int n = n0 + wn * 64 + j * 16 + ln;
        ncol[j] = n;
        sc[j] = scale[n];
        zv[j] = zp[n];
        bv[j] = bias[n];
    }
#pragma unroll
    for (int i = 0; i < 8; ++i) {
#pragma unroll
        for (int r = 0; r < 4; ++r) {
            const int m = m0 + wm * 128 + i * 16 + q * 4 + r;
            const float rsm = rowsum[m];
            const size_t rowoff = (size_t)m * N_DIM;
#pragma unroll
            for (int j = 0; j < 4; ++j) {
                out[rowoff + ncol[j]] = sc[j] * (acc[i][j][r] - zv[j] * rsm) + bv[j];
            }
        }
    }
}

extern "C" void kernel_launch(void* const* d_in, const int* in_sizes, int n_in,
                              void* d_out, int out_size, void* d_ws, size_t ws_size,
                              hipStream_t stream) {
    const float* X     = (const float*)d_in[0];
    const int*   Wq    = (const int*)d_in[1];
    const float* scale = (const float*)d_in[2];
    const float* zp    = (const float*)d_in[3];
    const float* bias  = (const float*)d_in[4];
    float* out = (float*)d_out;

    // ws layout: Wh (90,177,536 B) | Xh (67,108,864 B) | rowsum (32 KB)
    f16* Wh = (f16*)d_ws;
    f16* Xh = (f16*)((char*)d_ws + (size_t)N_DIM * K_DIM * 2);
    float* rowsum = (float*)((char*)d_ws + (size_t)N_DIM * K_DIM * 2 + (size_t)M_DIM * K_DIM * 2);

    static bool attr_done = false;
    if (!attr_done) {
        (void)hipFuncSetAttribute((const void*)qlin_gemm,
                                  hipFuncAttributeMaxDynamicSharedMemorySize, 131072);
        attr_done = true;
    }

    convw_kernel<<<4096, 256, 0, stream>>>(Wq, Wh);
    convx_kernel<<<M_DIM, 256, 0, stream>>>(X, Xh, rowsum);

    dim3 grid(M_DIM / 256, N_DIM / 256);  // (32, 43): m-fastest for W stream-once
    qlin_gemm<<<grid, 512, 131072, stream>>>(Xh, Wh, scale, zp, bias, rowsum, out);
}